// Round 1
// 116.348 us; speedup vs baseline: 1.0131x; 1.0131x over previous
//
#include <hip/hip_runtime.h>

typedef __bf16 bf16x8 __attribute__((ext_vector_type(8)));
typedef float f32x4 __attribute__((ext_vector_type(4)));
typedef float f32x16 __attribute__((ext_vector_type(16)));

#define CC 256
#define HH 48
#define WW 64
#define HW (HH * WW)
#define NB 8
#define GW 21

// ---------------------------------------------------------------------------
// Prepass: BOTH inputs -> MFMA-fragment PARITY order
//   [b][y][cblk=c>>3][p=x&1][x2=x>>1][c&7] bf16
// so the main kernel can run two independent 32x32 parity GEMMs (the
// displacement x-stride is 2, so only even (colx-x) is ever used).
// in1 scaled by 2^-8 (exact in bf16) to fold the /sumelems.
// ---------------------------------------------------------------------------
__global__ __launch_bounds__(256) void prep_kernel(const float* __restrict__ in1,
                                                   const float* __restrict__ in2,
                                                   unsigned short* __restrict__ o1,
                                                   unsigned short* __restrict__ o2)
{
    __shared__ float lds[CC * 33];
    int blk  = blockIdx.x;
    int sel  = (blk >= 768);
    int blk2 = sel ? blk - 768 : blk;
    int b  = blk2 & 7;
    int st = blk2 >> 3;                // 0..95 spatial tile (32 pixels)
    int s0 = st * 32;
    const float* src = sel ? in2 : in1;
    unsigned short* dst = sel ? o2 : o1;
    float scale = sel ? 1.0f : (1.0f / 256.0f);

    int t = threadIdx.x;
    int sidx  = t & 31;
    int cbase = t >> 5;
    const float* sb = src + (size_t)b * CC * HW + s0;
    #pragma unroll
    for (int p = 0; p < 32; ++p) {
        int c = cbase + p * 8;
        lds[c * 33 + sidx] = sb[(size_t)c * HW + sidx] * scale;
    }
    __syncthreads();

    // fragment order: [(b*48+y)*32 + cblk][p][x2][8c]
    int y  = s0 >> 6;
    int xb = s0 & 63;                  // 0 or 32
    int s  = t & 31;
    int c8 = t >> 5;                   // 0..7
    unsigned short* db = dst + (size_t)(b * HH + y) * 32 * 64 * 8;
    int x = xb + s;
    int xoff = (x & 1) * 32 + (x >> 1);   // parity-major position within cblk
    #pragma unroll
    for (int it = 0; it < 4; ++it) {
        int cblk = it * 8 + c8;
        unsigned dw[4];
        #pragma unroll
        for (int d = 0; d < 4; ++d) {
            unsigned u0 = __builtin_bit_cast(unsigned, lds[(cblk * 8 + 2 * d) * 33 + s]);
            u0 += 0x7fffu + ((u0 >> 16) & 1u);
            unsigned u1 = __builtin_bit_cast(unsigned, lds[(cblk * 8 + 2 * d + 1) * 33 + s]);
            u1 += 0x7fffu + ((u1 >> 16) & 1u);
            dw[d] = (u0 >> 16) | (u1 & 0xffff0000u);
        }
        *(uint4*)(db + ((size_t)cblk * 64 + xoff) * 8) =
            make_uint4(dw[0], dw[1], dw[2], dw[3]);
    }
}

// ---------------------------------------------------------------------------
// Main: block = (b, ysrc, jg); 4 waves handle j = 6*w + jg. B row (32KB,
// parity-fragment order) staged once per block in LDS. A streamed from global
// with a depth-4 prefetch ring.
//
// R7->R8 (parity split): colx - x = 2*(jx-10) is ALWAYS EVEN, so the old
// 64x64 GEMM's odd-parity cross terms were 100% waste. Each wave now runs
// two independent 32x32x256 GEMMs (even-x rows x even-colx cols, odd x odd)
// -> 32 MFMAs/wave instead of 64, acc 2x f32x16 instead of 4x (-32 VGPR),
// identical operand traffic and bitwise-identical results on used entries.
// Epilogue: D_p^T in per-wave LDS; lane = x, p = lane&1, ce = xe + jx - 10.
// ---------------------------------------------------------------------------
__global__ __launch_bounds__(256, 4) void corr_kernel(const unsigned short* __restrict__ in1F,
                                                      const unsigned short* __restrict__ in2F,
                                                      float* __restrict__ out)
{
    __shared__ unsigned char smem[36864];        // B-stage 32KB, then 4x9216B D^T
    unsigned short* Bl = (unsigned short*)smem;

    int blk  = blockIdx.x;
    int b    = blk & 7;                          // batch == XCD affinity
    int t2   = blk >> 3;
    int ysrc = t2 / 6 - 20;                      // ysrc-major: locality window
    int jg   = t2 - (t2 / 6) * 6;                // 0..5
    int tid  = threadIdx.x;
    int w    = tid >> 6;
    int lane = tid & 63;

    int j  = 6 * w + jg;                         // {jg, jg+6, jg+12, jg+18}
    int yo = ysrc - 2 * (j - 10);
    bool jvalid = (j <= 20) && (yo >= 0) && (yo < HH);

    float* orow = jvalid
        ? out + (((size_t)(b * 441 + j * GW)) * HH + yo) * WW
        : out;

    if (ysrc < 0 || ysrc >= HH) {
        // in2 source row OOB -> these 21 output rows are zero
        if (jvalid) {
            #pragma unroll
            for (int jx = 0; jx < GW; ++jx)
                __builtin_nontemporal_store(0.0f, orow + (size_t)jx * HW + lane);
        }
        return;                                  // whole block exits before barriers
    }

    int l31 = lane & 31;
    int q2  = lane >> 5;

    // A fragment base (cblk = kk*2+q2, parity p, m = l31): lane-linear 16B.
    // per-cblk stride = 2*32*8 = 512 ushorts; parity stride = 256.
    const unsigned short* arow = jvalid
        ? in1F + ((size_t)(b * HH + yo) * 32 + q2) * 512 + (size_t)l31 * 8
        : in1F;

    // ---- warm-up A loads BEFORE the staging barrier (overlap latency) ----
    bf16x8 Ab[4][2], Bb[2][2];
    if (jvalid) {
        #pragma unroll
        for (int kr = 0; kr < 3; ++kr)
            #pragma unroll
            for (int p = 0; p < 2; ++p)
                Ab[kr][p] = *(const bf16x8*)(arow + (size_t)kr * 1024 + p * 256);
    }

    // ---- stage B row (fragment order, linear 32KB copy) ----
    {
        const unsigned short* bsrc = in2F + (size_t)(b * HH + ysrc) * (32 * 64 * 8);
        #pragma unroll
        for (int it = 0; it < 8; ++it) {
            size_t off = ((size_t)it * 256 + tid) * 8;   // ushorts; 16B/thread
            *(uint4*)(Bl + off) = *(const uint4*)(bsrc + off);
        }
    }
    __syncthreads();

    f32x16 acc[2];
    if (jvalid) {
        const unsigned short* brow = Bl + (size_t)q2 * 512 + (size_t)l31 * 8;

        acc[0] = (f32x16)(0.0f);
        acc[1] = (f32x16)(0.0f);

        #pragma unroll
        for (int p = 0; p < 2; ++p)
            Bb[0][p] = *(const bf16x8*)(brow + p * 256);

        #pragma unroll
        for (int kk = 0; kk < 16; ++kk) {
            if (kk < 13) {
                #pragma unroll
                for (int p = 0; p < 2; ++p)
                    Ab[(kk + 3) & 3][p] =
                        *(const bf16x8*)(arow + (size_t)(kk + 3) * 1024 + p * 256);
            }
            if (kk < 15) {
                #pragma unroll
                for (int p = 0; p < 2; ++p)
                    Bb[(kk + 1) & 1][p] =
                        *(const bf16x8*)(brow + (size_t)(kk + 1) * 1024 + p * 256);
            }
            #pragma unroll
            for (int p = 0; p < 2; ++p)
                acc[p] = __builtin_amdgcn_mfma_f32_32x32x16_bf16(
                    Ab[kk & 3][p], Bb[kk & 1][p], acc[p], 0, 0, 0);
        }
    }

    __syncthreads();                             // B region dead; reuse for D^T

    if (!jvalid) return;

    // Epilogue: dump both parity D^T into wave-private LDS, band-extract.
    // 32x32 C layout: col = l31 (n = ce), row = (r&3) + 8*(r>>2) + 4*q2 (m = xe).
    float* dtw = (float*)smem + w * 2304;        // [p][32 ce][36] per wave
    #pragma unroll
    for (int p = 0; p < 2; ++p) {
        #pragma unroll
        for (int rq = 0; rq < 4; ++rq) {
            f32x4 v = { acc[p][4 * rq], acc[p][4 * rq + 1],
                        acc[p][4 * rq + 2], acc[p][4 * rq + 3] };
            *(f32x4*)(dtw + (size_t)(p * 32 + l31) * 36 + rq * 8 + q2 * 4) = v;
        }
    }

    int xe = lane >> 1;                          // x = 2*xe + pp
    int pp = lane & 1;
    #pragma unroll
    for (int jx = 0; jx < GW; ++jx) {
        int ce = xe + jx - 10;                   // colx = 2*ce + pp
        float v = (ce >= 0 && ce < 32) ? dtw[(size_t)(pp * 32 + ce) * 36 + xe] : 0.0f;
        __builtin_nontemporal_store(v, orow + (size_t)jx * HW + lane);
    }
}

extern "C" void kernel_launch(void* const* d_in, const int* in_sizes, int n_in,
                              void* d_out, int out_size, void* d_ws, size_t ws_size,
                              hipStream_t stream)
{
    (void)in_sizes; (void)n_in; (void)out_size; (void)ws_size;
    const float* in1 = (const float*)d_in[0];
    const float* in2 = (const float*)d_in[1];
    float* out = (float*)d_out;

    unsigned short* in1F = (unsigned short*)d_ws;                 // 12.6 MB
    unsigned short* in2F = in1F + (size_t)NB * HW * CC;           // 12.6 MB

    prep_kernel<<<dim3(1536), dim3(256), 0, stream>>>(in1, in2, in1F, in2F);
    corr_kernel<<<dim3(NB * 88 * 6), dim3(256), 0, stream>>>(in1F, in2F, out);
}